// Round 14
// baseline (149.648 us; speedup 1.0000x reference)
//
#include <hip/hip_runtime.h>
#include <hip/hip_bf16.h>
#include <cstdint>

#define B_   2
#define T_   2048
#define C_   1024
#define NH_  16
#define HS_  64
#define WIN_ 256
#define M_   (B_*T_)   // 4096

typedef __attribute__((ext_vector_type(8)))  short          short8;
typedef __attribute__((ext_vector_type(8)))  unsigned short ushortx8;
typedef __attribute__((ext_vector_type(8)))  __bf16         bf16x8;
typedef __attribute__((ext_vector_type(4)))  float          floatx4;
typedef __attribute__((ext_vector_type(16))) float          floatx16;

__device__ __forceinline__ unsigned short f2bf(float f) {
    union { float f; uint32_t u; } v; v.f = f;
    uint32_t r = (v.u + 0x7FFFu + ((v.u >> 16) & 1u)) >> 16;
    return (unsigned short)r;
}

__device__ __forceinline__ floatx4 mfma16(short8 a, short8 b, floatx4 c) {
    return __builtin_amdgcn_mfma_f32_16x16x32_bf16(
        __builtin_bit_cast(bf16x8, a), __builtin_bit_cast(bf16x8, b), c, 0, 0, 0);
}
__device__ __forceinline__ floatx16 mfma32(short8 a, short8 b, floatx16 c) {
    return __builtin_amdgcn_mfma_f32_32x32x16_bf16(
        __builtin_bit_cast(bf16x8, a), __builtin_bit_cast(bf16x8, b), c, 0, 0, 0);
}

__device__ __forceinline__ void async16(const void* g, void* l) {
    __builtin_amdgcn_global_load_lds(
        (const __attribute__((address_space(1))) void*)g,
        (__attribute__((address_space(3))) void*)l, 16, 0, 0);
}

// ---------------------------------------------------------------------------
// Fused prep (x convert + both weight transposes) — Round-0 exact
// ---------------------------------------------------------------------------
#define NB_CONV 4096
#define NB_WA   768
#define NB_WP   256

__device__ void transpose_tile(const float* __restrict__ in, unsigned short* __restrict__ out,
                               int K, int N, int kt, int nt, unsigned short (*tile)[65])
{
    const int k0 = kt * 64, n0 = nt * 64;
    const int tr = threadIdx.x >> 4;
    const int tc = (threadIdx.x & 15) * 4;
    #pragma unroll
    for (int it = 0; it < 4; it++) {
        int row = tr + it * 16;
        float4 v = *(const float4*)&in[(size_t)(k0 + row) * N + n0 + tc];
        tile[row][tc + 0] = f2bf(v.x);
        tile[row][tc + 1] = f2bf(v.y);
        tile[row][tc + 2] = f2bf(v.z);
        tile[row][tc + 3] = f2bf(v.w);
    }
    __syncthreads();
    #pragma unroll
    for (int it = 0; it < 4; it++) {
        int nrow = tr + it * 16;
        ushort4 h;
        h.x = tile[tc + 0][nrow]; h.y = tile[tc + 1][nrow];
        h.z = tile[tc + 2][nrow]; h.w = tile[tc + 3][nrow];
        *(ushort4*)&out[(size_t)(n0 + nrow) * K + k0 + tc] = h;
    }
}

__global__ __launch_bounds__(256)
void prep_kernel(const float* __restrict__ x, const float* __restrict__ W_attn,
                 const float* __restrict__ W_proj,
                 unsigned short* __restrict__ xb, unsigned short* __restrict__ Wa_t,
                 unsigned short* __restrict__ Wp_t)
{
    __shared__ unsigned short tile[64][65];
    const int bid = blockIdx.x;
    if (bid < NB_CONV) {
        int i = (bid * 256 + threadIdx.x) * 4;
        float4 v = *(const float4*)&x[i];
        ushort4 h;
        h.x = f2bf(v.x); h.y = f2bf(v.y); h.z = f2bf(v.z); h.w = f2bf(v.w);
        *(ushort4*)&xb[i] = h;
    } else if (bid < NB_CONV + NB_WA) {
        int idx = bid - NB_CONV;
        transpose_tile(W_attn, Wa_t, C_, 3 * C_, idx / 48, idx % 48, tile);
    } else {
        int idx = bid - NB_CONV - NB_WA;
        transpose_tile(W_proj, Wp_t, C_, C_, idx / 16, idx % 16, tile);
    }
}

// ---------------------------------------------------------------------------
// QKV GEMM: Round-0 exact. 128x128, MT=2, 4 waves, BK=64, single-buffered.
// Established local optimum (R0/R2/R4/R6/R8/R12): time set by blocks/CU
// (grid 768 = 3 blk/CU at 100% machine util); BK=128 drops to 2 blk/CU and
// regresses (R12); intra-block schedule polish is null. ~45 us.
// ---------------------------------------------------------------------------
template<int MT, bool OUT_BF16, bool VSPLIT>
__global__ __launch_bounds__(256)
void gemm32(const unsigned short* __restrict__ A,
            const unsigned short* __restrict__ Bt,
            void* __restrict__ Cp, unsigned short* __restrict__ vt,
            int M, int N, int K)
{
    constexpr int BK = 64;
    constexpr int BM = 64 * MT;
    __shared__ unsigned short As[BM * BK];
    __shared__ unsigned short Bs[128 * BK];

    const int tid  = threadIdx.x;
    const int lane = tid & 63;
    const int wave = tid >> 6;
    const int l32  = lane & 31;
    const int hi   = lane >> 5;
    const int px   = l32 & 7;
    const int wm   = (wave & 1) * 32 * MT;
    const int wn   = (wave >> 1) * 64;
    const int m0   = blockIdx.y * BM;
    const int n0   = blockIdx.x * 128;

    const int ri = lane >> 3;
    const int pg = lane & 7;
    const int gg = pg ^ ri;

    floatx16 acc[MT][2];
    #pragma unroll
    for (int i = 0; i < MT; i++)
        #pragma unroll
        for (int j = 0; j < 2; j++) acc[i][j] = (floatx16)(0.f);

    const unsigned short* gA = &A[(size_t)(m0 + wave * 8 + ri) * K + gg * 8];
    const unsigned short* gB = &Bt[(size_t)(n0 + wave * 8 + ri) * K + gg * 8];
    unsigned short* lA = &As[(wave * 8) * BK];
    unsigned short* lB = &Bs[(wave * 8) * BK];

    for (int k0 = 0; k0 < K; k0 += BK) {
        #pragma unroll
        for (int s = 0; s < 2 * MT; s++)
            async16(gA + k0 + (size_t)s * 32 * K, lA + s * 32 * BK);
        #pragma unroll
        for (int s = 0; s < 4; s++)
            async16(gB + k0 + (size_t)s * 32 * K, lB + s * 32 * BK);
        __syncthreads();

        #pragma unroll
        for (int ks = 0; ks < 4; ks++) {
            short8 af[MT], bfr[2];
            #pragma unroll
            for (int i = 0; i < MT; i++) {
                int r = wm + i * 32 + l32;
                int p = (ks * 2 + hi) ^ px;
                af[i] = *(const short8*)(&As[r * BK + p * 8]);
            }
            #pragma unroll
            for (int j = 0; j < 2; j++) {
                int r = wn + j * 32 + l32;
                int p = (ks * 2 + hi) ^ px;
                bfr[j] = *(const short8*)(&Bs[r * BK + p * 8]);
            }
            #pragma unroll
            for (int i = 0; i < MT; i++)
                #pragma unroll
                for (int j = 0; j < 2; j++)
                    acc[i][j] = mfma32(af[i], bfr[j], acc[i][j]);
        }
        __syncthreads();
    }

    #pragma unroll
    for (int i = 0; i < MT; i++)
        #pragma unroll
        for (int j = 0; j < 2; j++) {
            const int col  = n0 + wn + j * 32 + l32;
            const int row0 = m0 + wm + i * 32 + 4 * hi;
            if (VSPLIT && col >= 2 * C_) {
                const int hd = col - 2 * C_;
                const int hh = hd >> 6, d = hd & 63;
                #pragma unroll
                for (int g = 0; g < 4; g++) {
                    int rowg = row0 + 8 * g;
                    int bb = rowg >> 11, t = rowg & (T_ - 1);
                    ushort4 h4;
                    h4.x = f2bf(acc[i][j][g * 4 + 0]);
                    h4.y = f2bf(acc[i][j][g * 4 + 1]);
                    h4.z = f2bf(acc[i][j][g * 4 + 2]);
                    h4.w = f2bf(acc[i][j][g * 4 + 3]);
                    *(ushort4*)&vt[((size_t)(bb * NH_ + hh) * 64 + d) * T_ + t] = h4;
                }
            } else {
                #pragma unroll
                for (int g = 0; g < 4; g++)
                    #pragma unroll
                    for (int rr = 0; rr < 4; rr++) {
                        int row = row0 + 8 * g + rr;
                        if (OUT_BF16)
                            ((unsigned short*)Cp)[(size_t)row * N + col] = f2bf(acc[i][j][g * 4 + rr]);
                        else
                            ((float*)Cp)[(size_t)row * N + col] = acc[i][j][g * 4 + rr];
                    }
            }
        }
}

// ---------------------------------------------------------------------------
// proj GEMM: R11 exact. 64x64 tile, BK=128 — halved drain/barrier events at
// unchanged occupancy (32 KB LDS, 4 blk/CU). Validated -1.3 us (R11).
// ---------------------------------------------------------------------------
__global__ __launch_bounds__(256)
void gemmP(const unsigned short* __restrict__ A,
           const unsigned short* __restrict__ Bt,
           float* __restrict__ Cp, int M, int N, int K)
{
    constexpr int BK = 128;
    __shared__ unsigned short As[64 * BK];   // 16 KB
    __shared__ unsigned short Bs[64 * BK];   // 16 KB

    const int tid  = threadIdx.x;
    const int lane = tid & 63;
    const int wave = tid >> 6;            // 0..3
    const int l32  = lane & 31;
    const int hi   = lane >> 5;
    const int px   = l32 & 7;
    const int wm   = (wave & 1) * 32;     // 2 waves along M
    const int wn   = (wave >> 1) * 32;    // 2 waves along N
    const int m0   = blockIdx.y * 64;
    const int n0   = blockIdx.x * 64;

    // DMA lane mapping for 256-B rows: 4 rows x 16 granules per wave-pass
    const int ri4 = lane >> 4;            // row within pass (0..3)
    const int pg4 = lane & 15;            // granule within 256-B row
    const int rowlow = (wave * 4 + ri4) & 7;
    const int gg4 = (pg4 & 8) | ((pg4 & 7) ^ rowlow);

    floatx16 acc = (floatx16)(0.f);

    const unsigned short* gA = &A[(size_t)(m0 + wave * 4 + ri4) * K + gg4 * 8];
    const unsigned short* gB = &Bt[(size_t)(n0 + wave * 4 + ri4) * K + gg4 * 8];
    unsigned short* lA = &As[(wave * 4) * BK];
    unsigned short* lB = &Bs[(wave * 4) * BK];

    for (int k0 = 0; k0 < K; k0 += BK) {
        // each wave-pass fills 4 full 256-B rows; 4 passes x 4 waves = 64 rows
        #pragma unroll
        for (int s = 0; s < 4; s++)
            async16(gA + k0 + (size_t)s * 16 * K, lA + s * 16 * BK);
        #pragma unroll
        for (int s = 0; s < 4; s++)
            async16(gB + k0 + (size_t)s * 16 * K, lB + s * 16 * BK);
        __syncthreads();

        #pragma unroll
        for (int ks = 0; ks < 8; ks++) {
            const int c = ks * 2 + hi;                       // global granule
            const int p = (((c & 7) ^ px) | (c & 8)) * 8;    // per-half XOR
            short8 af = *(const short8*)(&As[(wm + l32) * BK + p]);
            short8 bf = *(const short8*)(&Bs[(wn + l32) * BK + p]);
            acc = mfma32(af, bf, acc);
        }
        __syncthreads();
    }

    const int col  = n0 + wn + l32;
    const int row0 = m0 + wm + 4 * hi;
    #pragma unroll
    for (int g = 0; g < 4; g++)
        #pragma unroll
        for (int rr = 0; rr < 4; rr++) {
            int row = row0 + 8 * g + rr;
            Cp[(size_t)row * N + col] = acc[g * 4 + rr];
        }
}

// ---------------------------------------------------------------------------
// Sliding-window attention, QBLK=128 + K/V DOUBLE-BUFFER with counted vmcnt.
// First occupancy-PRESERVING prefetch in the session: LDS 34.4 -> 50.4 KB
// still allows the grid-limited 2 blocks/CU (2 x 50.4 = 101 KB <= 160), so
// unlike R1 (6->3 blk/CU, regressed) the only change is that the per-tile
// serial {stage -> full-drain -> compute} becomes {stage(t+1) -> vmcnt(2)
// -> compute(t)}: the DMA latency hides under the previous tile's MFMA/exp.
// Sync scheme = R4's proven-correct pattern (issue-then-counted-wait, two
// barriers/tile; buf[cur^1]'s last readers passed the end-of-(t-1) barrier
// before stage(t+1) issues). Bytes, compute, FP order unchanged ->
// bit-identical numerics.
// ---------------------------------------------------------------------------
__global__ __launch_bounds__(512)
void attn_kernel(const unsigned short* __restrict__ qkv,
                 const unsigned short* __restrict__ vt,
                 unsigned short* __restrict__ y)
{
    __shared__ unsigned short Ks[2][64 * 64];   // [buf][key][d] swizzled
    __shared__ unsigned short Vs[2][64 * 64];   // [buf][d][key] swizzled
    __shared__ unsigned short Ps[8][16 * 72];   // per-wave P strip

    const int tid  = threadIdx.x;
    const int lane = tid & 63;
    const int wave = tid >> 6;                  // 0..7
    const int l16  = lane & 15;
    const int quad = lane >> 4;
    const int sw   = l16 & 7;                   // fragment swizzle key

    // XCD-aware decode of flat 512-block grid
    const int g  = blockIdx.x;
    const int yq = g >> 3;                      // 0..63
    const int hb = (g & 7) + 8 * (yq >> 4);     // 0..31
    const int qt = yq & 15;                     // 0..15
    const int h  = hb & 15;
    const int b  = hb >> 4;

    const int q0b = qt * 128;           // block q-tile base (128 rows)
    const int q0w = q0b + wave * 16;    // this wave's q-base
    const size_t base = (size_t)b * T_;
    const int ROW  = 3 * C_;
    const int qoff = h * HS_;
    const int koff = C_ + h * HS_;
    const size_t vbase = ((size_t)(b * NH_ + h) * 64) * T_;
    unsigned short* Pstrip = Ps[wave];
    const float SC = 0.125f * 1.44269504f;

    // DMA lane mapping: lane = 8*ri + pg ; global granule gg = pg ^ ri
    const int ri = lane >> 3;
    const int gg = (lane & 7) ^ ri;

    // Q a-frags (once)
    short8 aq[2];
    #pragma unroll
    for (int ks = 0; ks < 2; ks++)
        aq[ks] = *(const short8*)&qkv[(base + q0w + l16) * ROW + qoff + ks * 32 + quad * 8];

    floatx4 O[4];
    #pragma unroll
    for (int j = 0; j < 4; j++) O[j] = (floatx4){0.f, 0.f, 0.f, 0.f};
    float psum[4] = {0.f, 0.f, 0.f, 0.f};

    int kb_lo = q0b - (WIN_ - 1);
    kb_lo = (kb_lo > 0 ? kb_lo : 0) & ~63;
    const int kb_hi = q0b + 64;         // last tile containing keys <= q0b+127

    // stage K/V tile kb into buffer buf (2 async16 per lane: one K, one V row)
    auto stage = [&](int kb, int buf) {
        int row = wave * 8;
        async16(&qkv[(base + kb + row + ri) * ROW + koff + gg * 8],
                &Ks[buf][row * 64]);
        async16(&vt[vbase + (size_t)(row + ri) * T_ + kb + gg * 8],
                &Vs[buf][row * 64]);
    };

    stage(kb_lo, 0);
    int cur = 0;

    for (int kb = kb_lo; kb <= kb_hi; kb += 64) {
        if (kb < kb_hi) {
            stage(kb + 64, cur ^ 1);    // prefetch next tile (buf safe: its
                                        // readers passed end-of-prev barrier)
            asm volatile("s_waitcnt vmcnt(2)" ::: "memory");  // tile t landed
        } else {
            asm volatile("s_waitcnt vmcnt(0)" ::: "memory");
        }
        __builtin_amdgcn_s_barrier();   // tile t resident for all waves

        const unsigned short* Kc = Ks[cur];
        const unsigned short* Vc = Vs[cur];

        // wave-uniform skip: tiles outside [q0w-255, q0w+15] contribute 0.
        if (kb <= q0w + 15 && kb + 63 >= q0w - (WIN_ - 1)) {

            // ---- S = Q K^T ----
            floatx4 s[4];
            #pragma unroll
            for (int nt = 0; nt < 4; nt++) s[nt] = (floatx4){0.f, 0.f, 0.f, 0.f};
            #pragma unroll
            for (int ks = 0; ks < 2; ks++)
                #pragma unroll
                for (int nt = 0; nt < 4; nt++) {
                    short8 bk = *(const short8*)&Kc[(nt * 16 + l16) * 64
                                                    + (((ks * 4 + quad) ^ sw) * 8)];
                    s[nt] = mfma16(aq[ks], bk, s[nt]);
                }

            // ---- mask + exp + psum ----
            #pragma unroll
            for (int nt = 0; nt < 4; nt++)
                #pragma unroll
                for (int r = 0; r < 4; r++) {
                    int dist = (q0w + quad * 4 + r) - (kb + nt * 16 + l16);
                    float sv = ((unsigned)dist < (unsigned)WIN_) ? s[nt][r] * SC : -1e30f;
                    float e = exp2f(sv);
                    psum[r] += e;
                    s[nt][r] = e;
                }

            // ---- P roundtrip (wave-private) ----
            #pragma unroll
            for (int nt = 0; nt < 4; nt++)
                #pragma unroll
                for (int r = 0; r < 4; r++)
                    Pstrip[(quad * 4 + r) * 72 + nt * 16 + l16] = f2bf(s[nt][r]);

            // ---- O += P @ V ----
            #pragma unroll
            for (int ks = 0; ks < 2; ks++) {
                short8 ap = *(const short8*)&Pstrip[l16 * 72 + ks * 32 + quad * 8];
                #pragma unroll
                for (int jt = 0; jt < 4; jt++) {
                    short8 bv = *(const short8*)&Vc[(jt * 16 + l16) * 64
                                                    + (((ks * 4 + quad) ^ sw) * 8)];
                    O[jt] = mfma16(ap, bv, O[jt]);
                }
            }
        }

        asm volatile("" ::: "memory");
        __builtin_amdgcn_s_barrier();   // all waves done reading buf[cur]
        cur ^= 1;
    }

    // ---- row-sum reduce ----
    #pragma unroll
    for (int r = 0; r < 4; r++) {
        #pragma unroll
        for (int off = 8; off >= 1; off >>= 1)
            psum[r] += __shfl_xor(psum[r], off, 64);
    }

    // ---- epilogue via per-wave strip, coalesced ushort8 writes ----
    #pragma unroll
    for (int jt = 0; jt < 4; jt++)
        #pragma unroll
        for (int r = 0; r < 4; r++)
            Pstrip[(quad * 4 + r) * 72 + jt * 16 + l16] = f2bf(O[jt][r] / psum[r]);
    #pragma unroll
    for (int it = 0; it < 2; it++) {
        int c = lane + 64 * it;
        int qr = c >> 3, dc = (c & 7) * 8;
        *(ushortx8*)&y[(base + q0w + qr) * C_ + qoff + dc] =
            *(const ushortx8*)&Pstrip[qr * 72 + dc];
    }
}

// ---------------------------------------------------------------------------
extern "C" void kernel_launch(void* const* d_in, const int* in_sizes, int n_in,
                              void* d_out, int out_size, void* d_ws, size_t ws_size,
                              hipStream_t stream)
{
    const float* x      = (const float*)d_in[0];
    const float* W_attn = (const float*)d_in[1];
    const float* W_proj = (const float*)d_in[2];
    float* out = (float*)d_out;

    unsigned short* xb   = (unsigned short*)d_ws;                 // [M][C]      8 MB
    unsigned short* Wa_t = xb   + (size_t)M_ * C_;                // [3C][C]     6 MB
    unsigned short* Wp_t = Wa_t + (size_t)3 * C_ * C_;            // [C][C]      2 MB
    unsigned short* qkv  = Wp_t + (size_t)C_ * C_;                // [M][3C]    24 MB (Q,K)
    unsigned short* y    = qkv  + (size_t)M_ * 3 * C_;            // [M][C]      8 MB
    unsigned short* vtg  = y    + (size_t)M_ * C_;                // [B][NH][64][T] 8 MB

    dim3 blk(256);
    prep_kernel<<<NB_CONV + NB_WA + NB_WP, blk, 0, stream>>>(x, W_attn, W_proj, xb, Wa_t, Wp_t);
    // QKV GEMM: Round-0 exact (local optimum: 3 blk/CU, BK=64, 100% util)
    gemm32<2, true, true><<<dim3((3 * C_) / 128, M_ / 128), blk, 0, stream>>>(
        xb, Wa_t, qkv, vtg, M_, 3 * C_, C_);
    // attn: QBLK=128 + occupancy-preserving K/V double-buffer (counted vmcnt)
    attn_kernel<<<(T_ / 128) * NH_ * B_, dim3(512), 0, stream>>>(qkv, vtg, y);
    // proj GEMM: R11 exact (64x64, BK=128, occupancy-preserving drain halving)
    gemmP<<<dim3(C_ / 64, M_ / 64), blk, 0, stream>>>(
        y, Wp_t, out, M_, C_, C_);
}

// Round 15
// 146.672 us; speedup vs baseline: 1.0203x; 1.0203x over previous
//
#include <hip/hip_runtime.h>
#include <hip/hip_bf16.h>
#include <cstdint>

#define B_   2
#define T_   2048
#define C_   1024
#define NH_  16
#define HS_  64
#define WIN_ 256
#define M_   (B_*T_)   // 4096

typedef __attribute__((ext_vector_type(8)))  short          short8;
typedef __attribute__((ext_vector_type(8)))  unsigned short ushortx8;
typedef __attribute__((ext_vector_type(8)))  __bf16         bf16x8;
typedef __attribute__((ext_vector_type(4)))  float          floatx4;
typedef __attribute__((ext_vector_type(16))) float          floatx16;

__device__ __forceinline__ unsigned short f2bf(float f) {
    union { float f; uint32_t u; } v; v.f = f;
    uint32_t r = (v.u + 0x7FFFu + ((v.u >> 16) & 1u)) >> 16;
    return (unsigned short)r;
}

__device__ __forceinline__ floatx4 mfma16(short8 a, short8 b, floatx4 c) {
    return __builtin_amdgcn_mfma_f32_16x16x32_bf16(
        __builtin_bit_cast(bf16x8, a), __builtin_bit_cast(bf16x8, b), c, 0, 0, 0);
}
__device__ __forceinline__ floatx16 mfma32(short8 a, short8 b, floatx16 c) {
    return __builtin_amdgcn_mfma_f32_32x32x16_bf16(
        __builtin_bit_cast(bf16x8, a), __builtin_bit_cast(bf16x8, b), c, 0, 0, 0);
}

__device__ __forceinline__ void async16(const void* g, void* l) {
    __builtin_amdgcn_global_load_lds(
        (const __attribute__((address_space(1))) void*)g,
        (__attribute__((address_space(3))) void*)l, 16, 0, 0);
}

// ---------------------------------------------------------------------------
// Fused prep (x convert + both weight transposes) — Round-0 exact
// ---------------------------------------------------------------------------
#define NB_CONV 4096
#define NB_WA   768
#define NB_WP   256

__device__ void transpose_tile(const float* __restrict__ in, unsigned short* __restrict__ out,
                               int K, int N, int kt, int nt, unsigned short (*tile)[65])
{
    const int k0 = kt * 64, n0 = nt * 64;
    const int tr = threadIdx.x >> 4;
    const int tc = (threadIdx.x & 15) * 4;
    #pragma unroll
    for (int it = 0; it < 4; it++) {
        int row = tr + it * 16;
        float4 v = *(const float4*)&in[(size_t)(k0 + row) * N + n0 + tc];
        tile[row][tc + 0] = f2bf(v.x);
        tile[row][tc + 1] = f2bf(v.y);
        tile[row][tc + 2] = f2bf(v.z);
        tile[row][tc + 3] = f2bf(v.w);
    }
    __syncthreads();
    #pragma unroll
    for (int it = 0; it < 4; it++) {
        int nrow = tr + it * 16;
        ushort4 h;
        h.x = tile[tc + 0][nrow]; h.y = tile[tc + 1][nrow];
        h.z = tile[tc + 2][nrow]; h.w = tile[tc + 3][nrow];
        *(ushort4*)&out[(size_t)(n0 + nrow) * K + k0 + tc] = h;
    }
}

__global__ __launch_bounds__(256)
void prep_kernel(const float* __restrict__ x, const float* __restrict__ W_attn,
                 const float* __restrict__ W_proj,
                 unsigned short* __restrict__ xb, unsigned short* __restrict__ Wa_t,
                 unsigned short* __restrict__ Wp_t)
{
    __shared__ unsigned short tile[64][65];
    const int bid = blockIdx.x;
    if (bid < NB_CONV) {
        int i = (bid * 256 + threadIdx.x) * 4;
        float4 v = *(const float4*)&x[i];
        ushort4 h;
        h.x = f2bf(v.x); h.y = f2bf(v.y); h.z = f2bf(v.z); h.w = f2bf(v.w);
        *(ushort4*)&xb[i] = h;
    } else if (bid < NB_CONV + NB_WA) {
        int idx = bid - NB_CONV;
        transpose_tile(W_attn, Wa_t, C_, 3 * C_, idx / 48, idx % 48, tile);
    } else {
        int idx = bid - NB_CONV - NB_WA;
        transpose_tile(W_proj, Wp_t, C_, C_, idx / 16, idx % 16, tile);
    }
}

// ---------------------------------------------------------------------------
// QKV GEMM: Round-0 exact. 128x128, MT=2, 4 waves, BK=64, single-buffered.
// Established local optimum across R0/R2/R4/R6/R8/R12: runtime is set by
// blocks/CU (grid 768 = 3 blk/CU, full machine); BK=128 (2 blk/CU) regresses;
// dbuf/counted-vmcnt/ring-3 schedule polish is null at every occupancy tried.
// ~45 us (573 TF).
// ---------------------------------------------------------------------------
template<int MT, bool OUT_BF16, bool VSPLIT>
__global__ __launch_bounds__(256)
void gemm32(const unsigned short* __restrict__ A,
            const unsigned short* __restrict__ Bt,
            void* __restrict__ Cp, unsigned short* __restrict__ vt,
            int M, int N, int K)
{
    constexpr int BK = 64;
    constexpr int BM = 64 * MT;
    __shared__ unsigned short As[BM * BK];
    __shared__ unsigned short Bs[128 * BK];

    const int tid  = threadIdx.x;
    const int lane = tid & 63;
    const int wave = tid >> 6;
    const int l32  = lane & 31;
    const int hi   = lane >> 5;
    const int px   = l32 & 7;
    const int wm   = (wave & 1) * 32 * MT;
    const int wn   = (wave >> 1) * 64;
    const int m0   = blockIdx.y * BM;
    const int n0   = blockIdx.x * 128;

    const int ri = lane >> 3;
    const int pg = lane & 7;
    const int gg = pg ^ ri;

    floatx16 acc[MT][2];
    #pragma unroll
    for (int i = 0; i < MT; i++)
        #pragma unroll
        for (int j = 0; j < 2; j++) acc[i][j] = (floatx16)(0.f);

    const unsigned short* gA = &A[(size_t)(m0 + wave * 8 + ri) * K + gg * 8];
    const unsigned short* gB = &Bt[(size_t)(n0 + wave * 8 + ri) * K + gg * 8];
    unsigned short* lA = &As[(wave * 8) * BK];
    unsigned short* lB = &Bs[(wave * 8) * BK];

    for (int k0 = 0; k0 < K; k0 += BK) {
        #pragma unroll
        for (int s = 0; s < 2 * MT; s++)
            async16(gA + k0 + (size_t)s * 32 * K, lA + s * 32 * BK);
        #pragma unroll
        for (int s = 0; s < 4; s++)
            async16(gB + k0 + (size_t)s * 32 * K, lB + s * 32 * BK);
        __syncthreads();

        #pragma unroll
        for (int ks = 0; ks < 4; ks++) {
            short8 af[MT], bfr[2];
            #pragma unroll
            for (int i = 0; i < MT; i++) {
                int r = wm + i * 32 + l32;
                int p = (ks * 2 + hi) ^ px;
                af[i] = *(const short8*)(&As[r * BK + p * 8]);
            }
            #pragma unroll
            for (int j = 0; j < 2; j++) {
                int r = wn + j * 32 + l32;
                int p = (ks * 2 + hi) ^ px;
                bfr[j] = *(const short8*)(&Bs[r * BK + p * 8]);
            }
            #pragma unroll
            for (int i = 0; i < MT; i++)
                #pragma unroll
                for (int j = 0; j < 2; j++)
                    acc[i][j] = mfma32(af[i], bfr[j], acc[i][j]);
        }
        __syncthreads();
    }

    #pragma unroll
    for (int i = 0; i < MT; i++)
        #pragma unroll
        for (int j = 0; j < 2; j++) {
            const int col  = n0 + wn + j * 32 + l32;
            const int row0 = m0 + wm + i * 32 + 4 * hi;
            if (VSPLIT && col >= 2 * C_) {
                const int hd = col - 2 * C_;
                const int hh = hd >> 6, d = hd & 63;
                #pragma unroll
                for (int g = 0; g < 4; g++) {
                    int rowg = row0 + 8 * g;
                    int bb = rowg >> 11, t = rowg & (T_ - 1);
                    ushort4 h4;
                    h4.x = f2bf(acc[i][j][g * 4 + 0]);
                    h4.y = f2bf(acc[i][j][g * 4 + 1]);
                    h4.z = f2bf(acc[i][j][g * 4 + 2]);
                    h4.w = f2bf(acc[i][j][g * 4 + 3]);
                    *(ushort4*)&vt[((size_t)(bb * NH_ + hh) * 64 + d) * T_ + t] = h4;
                }
            } else {
                #pragma unroll
                for (int g = 0; g < 4; g++)
                    #pragma unroll
                    for (int rr = 0; rr < 4; rr++) {
                        int row = row0 + 8 * g + rr;
                        if (OUT_BF16)
                            ((unsigned short*)Cp)[(size_t)row * N + col] = f2bf(acc[i][j][g * 4 + rr]);
                        else
                            ((float*)Cp)[(size_t)row * N + col] = acc[i][j][g * 4 + rr];
                    }
            }
        }
}

// ---------------------------------------------------------------------------
// proj GEMM: R11 exact. 64x64 tile, BK=128 — halves drain/barrier events at
// UNCHANGED occupancy (32 KB LDS, 4 blk/CU): the validated scope of the
// BK-growth lever (R11 -1.3 us; R12: regresses when occupancy drops).
// Swizzle: per-64-col-half granule-XOR; ks=0..7 read order reproduces two
// successive BK=64 tiles in the same FP order (bit-identical numerics).
// ---------------------------------------------------------------------------
__global__ __launch_bounds__(256)
void gemmP(const unsigned short* __restrict__ A,
           const unsigned short* __restrict__ Bt,
           float* __restrict__ Cp, int M, int N, int K)
{
    constexpr int BK = 128;
    __shared__ unsigned short As[64 * BK];   // 16 KB
    __shared__ unsigned short Bs[64 * BK];   // 16 KB

    const int tid  = threadIdx.x;
    const int lane = tid & 63;
    const int wave = tid >> 6;            // 0..3
    const int l32  = lane & 31;
    const int hi   = lane >> 5;
    const int px   = l32 & 7;
    const int wm   = (wave & 1) * 32;     // 2 waves along M
    const int wn   = (wave >> 1) * 32;    // 2 waves along N
    const int m0   = blockIdx.y * 64;
    const int n0   = blockIdx.x * 64;

    // DMA lane mapping for 256-B rows: 4 rows x 16 granules per wave-pass
    const int ri4 = lane >> 4;            // row within pass (0..3)
    const int pg4 = lane & 15;            // granule within 256-B row
    const int rowlow = (wave * 4 + ri4) & 7;
    const int gg4 = (pg4 & 8) | ((pg4 & 7) ^ rowlow);

    floatx16 acc = (floatx16)(0.f);

    const unsigned short* gA = &A[(size_t)(m0 + wave * 4 + ri4) * K + gg4 * 8];
    const unsigned short* gB = &Bt[(size_t)(n0 + wave * 4 + ri4) * K + gg4 * 8];
    unsigned short* lA = &As[(wave * 4) * BK];
    unsigned short* lB = &Bs[(wave * 4) * BK];

    for (int k0 = 0; k0 < K; k0 += BK) {
        // each wave-pass fills 4 full 256-B rows; 4 passes x 4 waves = 64 rows
        #pragma unroll
        for (int s = 0; s < 4; s++)
            async16(gA + k0 + (size_t)s * 16 * K, lA + s * 16 * BK);
        #pragma unroll
        for (int s = 0; s < 4; s++)
            async16(gB + k0 + (size_t)s * 16 * K, lB + s * 16 * BK);
        __syncthreads();

        #pragma unroll
        for (int ks = 0; ks < 8; ks++) {
            const int c = ks * 2 + hi;                       // global granule
            const int p = (((c & 7) ^ px) | (c & 8)) * 8;    // per-half XOR
            short8 af = *(const short8*)(&As[(wm + l32) * BK + p]);
            short8 bf = *(const short8*)(&Bs[(wn + l32) * BK + p]);
            acc = mfma32(af, bf, acc);
        }
        __syncthreads();
    }

    const int col  = n0 + wn + l32;
    const int row0 = m0 + wm + 4 * hi;
    #pragma unroll
    for (int g = 0; g < 4; g++)
        #pragma unroll
        for (int rr = 0; rr < 4; rr++) {
            int row = row0 + 8 * g + rr;
            Cp[(size_t)row * N + col] = acc[g * 4 + rr];
        }
}

// ---------------------------------------------------------------------------
// Sliding-window attention, QBLK=128 (R9 exact): one block = 128 q-rows,
// 8 waves (512 threads), single-buffered K/V staging (R14 measured the
// occupancy-preserving dbuf as null). K/V staging instrs per q -45%,
// barrier pairs per q -40% vs QBLK=64. Wave-uniform skip keeps numerics
// bit-identical (skipped tiles would contribute exp2f(-1e30)=0 everywhere).
// ---------------------------------------------------------------------------
__global__ __launch_bounds__(512)
void attn_kernel(const unsigned short* __restrict__ qkv,
                 const unsigned short* __restrict__ vt,
                 unsigned short* __restrict__ y)
{
    __shared__ unsigned short Ks[64 * 64];      // [key][d] swizzled
    __shared__ unsigned short Vs[64 * 64];      // [d][key] swizzled
    __shared__ unsigned short Ps[8][16 * 72];   // per-wave P strip

    const int tid  = threadIdx.x;
    const int lane = tid & 63;
    const int wave = tid >> 6;                  // 0..7
    const int l16  = lane & 15;
    const int quad = lane >> 4;
    const int sw   = l16 & 7;                   // fragment swizzle key

    // XCD-aware decode of flat 512-block grid
    const int g  = blockIdx.x;
    const int yq = g >> 3;                      // 0..63
    const int hb = (g & 7) + 8 * (yq >> 4);     // 0..31
    const int qt = yq & 15;                     // 0..15
    const int h  = hb & 15;
    const int b  = hb >> 4;

    const int q0b = qt * 128;           // block q-tile base (128 rows)
    const int q0w = q0b + wave * 16;    // this wave's q-base
    const size_t base = (size_t)b * T_;
    const int ROW  = 3 * C_;
    const int qoff = h * HS_;
    const int koff = C_ + h * HS_;
    const size_t vbase = ((size_t)(b * NH_ + h) * 64) * T_;
    unsigned short* Pstrip = Ps[wave];
    const float SC = 0.125f * 1.44269504f;

    // DMA lane mapping: lane = 8*ri + pg ; global granule gg = pg ^ ri
    const int ri = lane >> 3;
    const int gg = (lane & 7) ^ ri;

    // Q a-frags (once)
    short8 aq[2];
    #pragma unroll
    for (int ks = 0; ks < 2; ks++)
        aq[ks] = *(const short8*)&qkv[(base + q0w + l16) * ROW + qoff + ks * 32 + quad * 8];

    floatx4 O[4];
    #pragma unroll
    for (int j = 0; j < 4; j++) O[j] = (floatx4){0.f, 0.f, 0.f, 0.f};
    float psum[4] = {0.f, 0.f, 0.f, 0.f};

    int kb_lo = q0b - (WIN_ - 1);
    kb_lo = (kb_lo > 0 ? kb_lo : 0) & ~63;
    const int kb_hi = q0b + 64;         // last tile containing keys <= q0b+127

    for (int kb = kb_lo; kb <= kb_hi; kb += 64) {
        __syncthreads();   // all waves done reading previous tile
        // stage K/V tile: 8 waves x 8 rows, 128 B each (coalesced)
        {
            int row = wave * 8;
            async16(&qkv[(base + kb + row + ri) * ROW + koff + gg * 8],
                    &Ks[row * 64]);
            async16(&vt[vbase + (size_t)(row + ri) * T_ + kb + gg * 8],
                    &Vs[row * 64]);
        }
        __syncthreads();   // vmcnt drain -> tiles ready

        // wave-uniform skip: tiles outside [q0w-255, q0w+15] contribute 0.
        if (kb <= q0w + 15 && kb + 63 >= q0w - (WIN_ - 1)) {

            // ---- S = Q K^T ----
            floatx4 s[4];
            #pragma unroll
            for (int nt = 0; nt < 4; nt++) s[nt] = (floatx4){0.f, 0.f, 0.f, 0.f};
            #pragma unroll
            for (int ks = 0; ks < 2; ks++)
                #pragma unroll
                for (int nt = 0; nt < 4; nt++) {
                    short8 bk = *(const short8*)&Ks[(nt * 16 + l16) * 64
                                                    + (((ks * 4 + quad) ^ sw) * 8)];
                    s[nt] = mfma16(aq[ks], bk, s[nt]);
                }

            // ---- mask + exp + psum ----
            #pragma unroll
            for (int nt = 0; nt < 4; nt++)
                #pragma unroll
                for (int r = 0; r < 4; r++) {
                    int dist = (q0w + quad * 4 + r) - (kb + nt * 16 + l16);
                    float sv = ((unsigned)dist < (unsigned)WIN_) ? s[nt][r] * SC : -1e30f;
                    float e = exp2f(sv);
                    psum[r] += e;
                    s[nt][r] = e;
                }

            // ---- P roundtrip (wave-private) ----
            #pragma unroll
            for (int nt = 0; nt < 4; nt++)
                #pragma unroll
                for (int r = 0; r < 4; r++)
                    Pstrip[(quad * 4 + r) * 72 + nt * 16 + l16] = f2bf(s[nt][r]);

            // ---- O += P @ V ----
            #pragma unroll
            for (int ks = 0; ks < 2; ks++) {
                short8 ap = *(const short8*)&Pstrip[l16 * 72 + ks * 32 + quad * 8];
                #pragma unroll
                for (int jt = 0; jt < 4; jt++) {
                    short8 bv = *(const short8*)&Vs[(jt * 16 + l16) * 64
                                                    + (((ks * 4 + quad) ^ sw) * 8)];
                    O[jt] = mfma16(ap, bv, O[jt]);
                }
            }
        }
    }

    // ---- row-sum reduce ----
    #pragma unroll
    for (int r = 0; r < 4; r++) {
        #pragma unroll
        for (int off = 8; off >= 1; off >>= 1)
            psum[r] += __shfl_xor(psum[r], off, 64);
    }

    // ---- epilogue via per-wave strip, coalesced ushort8 writes ----
    #pragma unroll
    for (int jt = 0; jt < 4; jt++)
        #pragma unroll
        for (int r = 0; r < 4; r++)
            Pstrip[(quad * 4 + r) * 72 + jt * 16 + l16] = f2bf(O[jt][r] / psum[r]);
    #pragma unroll
    for (int it = 0; it < 2; it++) {
        int c = lane + 64 * it;
        int qr = c >> 3, dc = (c & 7) * 8;
        *(ushortx8*)&y[(base + q0w + qr) * C_ + qoff + dc] =
            *(const ushortx8*)&Pstrip[qr * 72 + dc];
    }
}

// ---------------------------------------------------------------------------
extern "C" void kernel_launch(void* const* d_in, const int* in_sizes, int n_in,
                              void* d_out, int out_size, void* d_ws, size_t ws_size,
                              hipStream_t stream)
{
    const float* x      = (const float*)d_in[0];
    const float* W_attn = (const float*)d_in[1];
    const float* W_proj = (const float*)d_in[2];
    float* out = (float*)d_out;

    unsigned short* xb   = (unsigned short*)d_ws;                 // [M][C]      8 MB
    unsigned short* Wa_t = xb   + (size_t)M_ * C_;                // [3C][C]     6 MB
    unsigned short* Wp_t = Wa_t + (size_t)3 * C_ * C_;            // [C][C]      2 MB
    unsigned short* qkv  = Wp_t + (size_t)C_ * C_;                // [M][3C]    24 MB (Q,K)
    unsigned short* y    = qkv  + (size_t)M_ * 3 * C_;            // [M][C]      8 MB
    unsigned short* vtg  = y    + (size_t)M_ * C_;                // [B][NH][64][T] 8 MB

    dim3 blk(256);
    prep_kernel<<<NB_CONV + NB_WA + NB_WP, blk, 0, stream>>>(x, W_attn, W_proj, xb, Wa_t, Wp_t);
    // QKV GEMM: Round-0 exact (local optimum: 3 blk/CU, BK=64, full machine)
    gemm32<2, true, true><<<dim3((3 * C_) / 128, M_ / 128), blk, 0, stream>>>(
        xb, Wa_t, qkv, vtg, M_, 3 * C_, C_);
    // attn: QBLK=128, single-buffered (R9 exact; R14 dbuf was null)
    attn_kernel<<<(T_ / 128) * NH_ * B_, dim3(512), 0, stream>>>(qkv, vtg, y);
    // proj GEMM: R11 exact (64x64, BK=128, occupancy-preserving drain halving)
    gemmP<<<dim3(C_ / 64, M_ / 64), blk, 0, stream>>>(
        y, Wp_t, out, M_, C_, C_);
}